// Round 16
// baseline (109.203 us; speedup 1.0000x reference)
//
#include <hip/hip_runtime.h>
#include <hip/hip_fp16.h>
#include <cmath>

#define B_ 2
#define X_ 128
#define Y_ 128
#define Z_ 128
#define C_ 8
#define ZC 1024         // Z_*C_ elements per (x,y) row
#define XS 131072       // Y_*ZC, stride of x in elements
#define BS 16777216     // X_*XS, stride of batch in elements
#define KTAPS 13
#define TAIL 6

struct Taps { float k[KTAPS]; };

typedef float  vf4 __attribute__((ext_vector_type(4)));   // clang vector: nt-ok
typedef unsigned int vu2 __attribute__((ext_vector_type(2)));

__device__ __forceinline__ float4 ld4(const float* p) {
    return *reinterpret_cast<const float4*>(p);
}
__device__ __forceinline__ float4 ntld4(const float* p) {
    vf4 r = __builtin_nontemporal_load(reinterpret_cast<const vf4*>(p));
    return make_float4(r.x, r.y, r.z, r.w);
}
__device__ __forceinline__ void st4(float* p, const float4& v) {
    *reinterpret_cast<float4*>(p) = v;
}
__device__ __forceinline__ float4 f4zero() { return make_float4(0.f, 0.f, 0.f, 0.f); }
__device__ __forceinline__ void fma4(float4& a, float s, const float4& b) {
    a.x = fmaf(s, b.x, a.x); a.y = fmaf(s, b.y, a.y);
    a.z = fmaf(s, b.z, a.z); a.w = fmaf(s, b.w, a.w);
}
// fp16 quad pack (8B), non-temporal store for the tmp stream
__device__ __forceinline__ void sth4_nt(__half* p, const float4& v) {
    __half2 lo = __floats2half2_rn(v.x, v.y);
    __half2 hi = __floats2half2_rn(v.z, v.w);
    vu2 u;
    u.x = *reinterpret_cast<unsigned int*>(&lo);
    u.y = *reinterpret_cast<unsigned int*>(&hi);
    __builtin_nontemporal_store(u, reinterpret_cast<vu2*>(p));
}
__device__ __forceinline__ float4 h4f(uint2 u) {
    __half2 lo = *reinterpret_cast<__half2*>(&u.x);
    __half2 hi = *reinterpret_cast<__half2*>(&u.y);
    float2 a = __half22float2(lo);
    float2 b = __half22float2(hi);
    return make_float4(a.x, a.y, b.x, b.y);
}

// ---------------- Pass 1: Y conv, max-TLP non-temporal stream ----------------
// R12 vs R14: register-window and DMA staging both run at exactly 3.35 TB/s
// mixed -> staging mechanism irrelevant; delivery rate is the binder.
// Two untested levers:
//  * occupancy: no pin, no launch_bounds(,1), no LDS -> compiler's ~64-VGPR
//    interleave at up to 8 waves/SIMD (copy-ubench-like TLP).
//  * nt loads/stores: bypass L1 allocation for the cold read; nt fp16 stores
//    keep tmp from polluting caches on the way out.
// XCD-chunked compact band kept (R12: FETCH 158->77MB); fp16 tmp kept (R14).
template <int T>
__global__ __launch_bounds__(256) void ystream(const float* __restrict__ src,
                                               __half* __restrict__ dst,
                                               Taps tp) {
    const int t  = threadIdx.x;
    const int zc = t << 2;
    // 4096 chunks; XCD-chunked bijective map (each XCD: 512 consecutive).
    const int g  = (blockIdx.x & 7) * 512 + (blockIdx.x >> 3);
    const int p  = g >> 4;                          // plane index (Y_/T = 16)
    const int y0 = (g & 15) * T;

    const float* sp = src + (size_t)p * XS + zc;
    __half*      dp = dst + (size_t)p * XS + zc;

    float4 v[T + 2 * TAIL];
#pragma unroll
    for (int i = 0; i < T + 2 * TAIL; ++i) {
        const int yy = y0 - TAIL + i;
        v[i] = (yy >= 0 && yy < Y_) ? ntld4(sp + (size_t)yy * ZC) : f4zero();
    }

#pragma unroll
    for (int j = 0; j < T; ++j) {
        float4 acc = f4zero();
#pragma unroll
        for (int i = 0; i < KTAPS; ++i) fma4(acc, tp.k[i], v[j + i]);
        sth4_nt(dp + (size_t)(y0 + j) * ZC, acc);
    }
}

// ------------- Pass 2: X-conv gather (fp16 L3-warm) + Z-conv via LDS ---------
// Unchanged from R14 (~33us). Block = one zc row at (b,y), x-window W=16;
// pinned 28-plane 8B-load burst (fp16 tmp L3-resident); per-x LDS row staging
// for Z; lgkmcnt-only barrier (no vmcnt drain). Output fp32.
template <int W, bool HSRC, bool DOZ>
__global__ __launch_bounds__(256, 1) void xzconv(const void* __restrict__ srcv,
                                                 float* __restrict__ dst,
                                                 Taps tp) {
    __shared__ float row[2][ZC];

    const int t   = threadIdx.x;
    const int gid = blockIdx.x;
    const int y   = (Y_ - 1) - (gid & (Y_ - 1));   // reversed: hit last-written tmp
    const int xw  = (gid >> 7) & (X_ / W - 1);
    const int b   = gid >> 10;

    const int x0   = xw * W;
    const size_t base = (size_t)b * BS + (size_t)y * ZC + (t << 2);
    const int z    = t >> 1;
    const int cw   = (t & 1) << 2;

    float4 v[W + 2 * TAIL];
    if (HSRC) {
        const __half* src = (const __half*)srcv;
        uint2 raw[W + 2 * TAIL];
#pragma unroll
        for (int i = 0; i < W + 2 * TAIL; ++i) {
            const int xx = x0 - TAIL + i;
            raw[i] = (xx >= 0 && xx < X_)
                   ? *reinterpret_cast<const uint2*>(src + base + (size_t)xx * XS)
                   : make_uint2(0u, 0u);
        }
#pragma unroll
        for (int i = 0; i < W + 2 * TAIL; ++i) {
            asm volatile("" : "+v"(raw[i].x), "+v"(raw[i].y));
        }
        __builtin_amdgcn_sched_barrier(0);
#pragma unroll
        for (int i = 0; i < W + 2 * TAIL; ++i) v[i] = h4f(raw[i]);
    } else {
        const float* src = (const float*)srcv;
#pragma unroll
        for (int i = 0; i < W + 2 * TAIL; ++i) {
            const int xx = x0 - TAIL + i;
            v[i] = (xx >= 0 && xx < X_) ? ld4(src + base + (size_t)xx * XS) : f4zero();
        }
#pragma unroll
        for (int i = 0; i < W + 2 * TAIL; ++i) {
            asm volatile("" : "+v"(v[i].x), "+v"(v[i].y), "+v"(v[i].z), "+v"(v[i].w));
        }
        __builtin_amdgcn_sched_barrier(0);
    }

    int pp = 0;
#pragma unroll
    for (int j = 0; j < W; ++j) {
        float4 acc = f4zero();
#pragma unroll
        for (int i = 0; i < KTAPS; ++i) fma4(acc, tp.k[i], v[j + i]);

        if (DOZ) {
            st4(&row[pp][t << 2], acc);
            asm volatile("s_waitcnt lgkmcnt(0)" ::: "memory");
            __builtin_amdgcn_s_barrier();
            __builtin_amdgcn_sched_barrier(0);

            float4 zacc = f4zero();
#pragma unroll
            for (int i = 0; i < KTAPS; ++i) {
                const int zz = z - TAIL + i;
                if (zz >= 0 && zz < Z_) {
                    fma4(zacc, tp.k[i], ld4(&row[pp][(zz << 3) + cw]));
                }
            }
            st4(dst + base + (size_t)(x0 + j) * XS, zacc);
            pp ^= 1;
        } else {
            st4(dst + base + (size_t)(x0 + j) * XS, acc);
        }
    }
}

// -------- Fallback-only: fused Y+Z, single plane per block, in-place-safe ----
template <int SEGY, int P>
__global__ __launch_bounds__(256) void yzconv_kernel(const float* __restrict__ src,
                                                     float* __restrict__ dst,
                                                     Taps tp) {
    __shared__ float row[2][ZC];

    const int t    = threadIdx.x;
    const int s    = blockIdx.x % SEGY;
    const int rest = blockIdx.x / SEGY;
    const int x    = rest & (X_ - 1);
    const int b    = rest >> 7;

    const int pbase = b * BS + x * XS;
    const int zc    = t << 2;
    const int z     = t >> 1;
    const int cw    = (t & 1) << 2;

    const int ylen = Y_ / SEGY;
    const int y0   = s * ylen;

    auto ldrow = [&](int yy) -> float4 {
        return (yy >= 0 && yy < Y_) ? ld4(src + pbase + yy * ZC + zc) : f4zero();
    };

    float4 w[KTAPS];
#pragma unroll
    for (int i = 0; i < KTAPS - 1; ++i) w[i] = ldrow(y0 - TAIL + i);
    float4 pf[P];
#pragma unroll
    for (int i = 0; i < P; ++i) pf[i] = ldrow(y0 + TAIL + i);

    int p = 0;
    for (int yy = 0; yy < ylen; yy += P) {
#pragma unroll
        for (int k = 0; k < P; ++k) {
            const int y = y0 + yy + k;
            w[KTAPS - 1] = pf[k];
            pf[k] = ldrow(y + TAIL + P);

            float4 acc = f4zero();
#pragma unroll
            for (int i = 0; i < KTAPS; ++i) fma4(acc, tp.k[i], w[i]);
            st4(&row[p][zc], acc);
            asm volatile("s_waitcnt lgkmcnt(0)" ::: "memory");
            __builtin_amdgcn_s_barrier();
            __builtin_amdgcn_sched_barrier(0);

            float4 zacc = f4zero();
#pragma unroll
            for (int i = 0; i < KTAPS; ++i) {
                const int zz = z - TAIL + i;
                if (zz >= 0 && zz < Z_) {
                    fma4(zacc, tp.k[i], ld4(&row[p][(zz << 3) + cw]));
                }
            }
            st4(dst + pbase + y * ZC + zc, zacc);

#pragma unroll
            for (int i = 0; i < KTAPS - 1; ++i) w[i] = w[i + 1];
            p ^= 1;
        }
    }
}

extern "C" void kernel_launch(void* const* d_in, const int* in_sizes, int n_in,
                              void* d_out, int out_size, void* d_ws, size_t ws_size,
                              hipStream_t stream) {
    const float* in = (const float*)d_in[0];
    float* out = (float*)d_out;

    // Gaussian taps: tail = int(2.0*3.0 + 0.5) = 6, K = 13, sigma = 2
    Taps tp;
    {
        float kv[KTAPS];
        float sum = 0.f;
        for (int i = 0; i < KTAPS; ++i) {
            const float xx = (float)(i - TAIL);
            kv[i] = expf(-0.5f * xx * xx / 4.0f);
            sum += kv[i];
        }
        for (int i = 0; i < KTAPS; ++i) tp.k[i] = kv[i] / sum;
    }

    const size_t need_bytes = (size_t)B_ * BS * sizeof(__half);  // 67 MB
    const bool use_ws = (ws_size >= need_bytes) && (d_ws != nullptr);

    if (use_ws) {
        __half* tmp = (__half*)d_ws;
        // Pass 1: max-TLP nt-stream Y conv, in (cold, fp32) -> tmp (fp16).
        ystream<8><<<4096, 256, 0, stream>>>(in, tmp, tp);
        // Pass 2: X gather (fp16 tmp, L3-resident) + Z via LDS -> out (fp32).
        xzconv<16, true, true><<<B_ * (X_ / 16) * Y_, 256, 0, stream>>>(tmp, out, tp);
    } else {
        // Fallback: fp32 X-only gather in->out, then in-place fused Y+Z.
        xzconv<16, false, false><<<B_ * (X_ / 16) * Y_, 256, 0, stream>>>(in, out, tp);
        yzconv_kernel<1, 4><<<B_ * X_, 256, 0, stream>>>(out, out, tp);
    }
}

// Round 17
// 95.647 us; speedup vs baseline: 1.1417x; 1.1417x over previous
//
#include <hip/hip_runtime.h>
#include <hip/hip_fp16.h>
#include <cmath>

#define B_ 2
#define X_ 128
#define Y_ 128
#define Z_ 128
#define C_ 8
#define ZC 1024         // Z_*C_ elements per (x,y) row
#define XS 131072       // Y_*ZC, stride of x in elements
#define BS 16777216     // X_*XS, stride of batch in elements
#define KTAPS 13
#define TAIL 6

struct Taps { float k[KTAPS]; };

__device__ __forceinline__ float4 ld4(const float* p) {
    return *reinterpret_cast<const float4*>(p);
}
__device__ __forceinline__ void st4(float* p, const float4& v) {
    *reinterpret_cast<float4*>(p) = v;
}
__device__ __forceinline__ float4 f4zero() { return make_float4(0.f, 0.f, 0.f, 0.f); }
__device__ __forceinline__ void fma4(float4& a, float s, const float4& b) {
    a.x = fmaf(s, b.x, a.x); a.y = fmaf(s, b.y, a.y);
    a.z = fmaf(s, b.z, a.z); a.w = fmaf(s, b.w, a.w);
}
// fp16 quad pack (8B), CACHEABLE store: tmp must land in L2/L3 for pass 2
// (R16 lesson: nt stores evicted tmp -> pass2 lost its L3-warm source, -16us).
__device__ __forceinline__ void sth4(__half* p, const float4& v) {
    __half2 lo = __floats2half2_rn(v.x, v.y);
    __half2 hi = __floats2half2_rn(v.z, v.w);
    uint2 u;
    u.x = *reinterpret_cast<unsigned int*>(&lo);
    u.y = *reinterpret_cast<unsigned int*>(&hi);
    *reinterpret_cast<uint2*>(p) = u;
}
__device__ __forceinline__ float4 h4f(uint2 u) {
    __half2 lo = *reinterpret_cast<__half2*>(&u.x);
    __half2 hi = *reinterpret_cast<__half2*>(&u.y);
    float2 a = __half22float2(lo);
    float2 b = __half22float2(hi);
    return make_float4(a.x, a.y, b.x, b.y);
}

// ---------------- Pass 1: Y conv, plain cached max-occupancy gather ----------
// Clean A/B cell: cached loads (halo absorbed by L2/L3), cached fp16 stores
// (tmp stays L3-warm), NO pin, NO launch_bounds cap, NO LDS/DMA -> compiler
// free to pick ~48-64 VGPR and high occupancy. XCD-chunked compact band kept
// (R12: FETCH 158->77MB). If this lands ~60us like R12(pinned)/R14(DMA),
// staging + occupancy are confirmed irrelevant and ~3.35 TB/s mixed is the
// structural cold-stream ceiling of this box.
template <int T>
__global__ void ystream(const float* __restrict__ src,
                        __half* __restrict__ dst,
                        Taps tp) {
    const int t  = threadIdx.x;
    const int zc = t << 2;
    // 4096 chunks; XCD-chunked bijective map (each XCD: 512 consecutive).
    const int g  = (blockIdx.x & 7) * 512 + (blockIdx.x >> 3);
    const int p  = g >> 4;                          // plane index (Y_/T = 16)
    const int y0 = (g & 15) * T;

    const float* sp = src + (size_t)p * XS + zc;
    __half*      dp = dst + (size_t)p * XS + zc;

    float4 v[T + 2 * TAIL];
#pragma unroll
    for (int i = 0; i < T + 2 * TAIL; ++i) {
        const int yy = y0 - TAIL + i;
        v[i] = (yy >= 0 && yy < Y_) ? ld4(sp + (size_t)yy * ZC) : f4zero();
    }

#pragma unroll
    for (int j = 0; j < T; ++j) {
        float4 acc = f4zero();
#pragma unroll
        for (int i = 0; i < KTAPS; ++i) fma4(acc, tp.k[i], v[j + i]);
        sth4(dp + (size_t)(y0 + j) * ZC, acc);
    }
}

// ------------- Pass 2: X-conv gather (fp16 L3-warm) + Z-conv via LDS ---------
// Unchanged from R14 (~33us). Block = one zc row at (b,y), x-window W=16;
// pinned 28-plane 8B-load burst (fp16 tmp L3-resident); per-x LDS row staging
// for Z; lgkmcnt-only barrier (no vmcnt drain). Output fp32.
template <int W, bool HSRC, bool DOZ>
__global__ __launch_bounds__(256, 1) void xzconv(const void* __restrict__ srcv,
                                                 float* __restrict__ dst,
                                                 Taps tp) {
    __shared__ float row[2][ZC];

    const int t   = threadIdx.x;
    const int gid = blockIdx.x;
    const int y   = (Y_ - 1) - (gid & (Y_ - 1));   // reversed: hit last-written tmp
    const int xw  = (gid >> 7) & (X_ / W - 1);
    const int b   = gid >> 10;

    const int x0   = xw * W;
    const size_t base = (size_t)b * BS + (size_t)y * ZC + (t << 2);
    const int z    = t >> 1;
    const int cw   = (t & 1) << 2;

    float4 v[W + 2 * TAIL];
    if (HSRC) {
        const __half* src = (const __half*)srcv;
        uint2 raw[W + 2 * TAIL];
#pragma unroll
        for (int i = 0; i < W + 2 * TAIL; ++i) {
            const int xx = x0 - TAIL + i;
            raw[i] = (xx >= 0 && xx < X_)
                   ? *reinterpret_cast<const uint2*>(src + base + (size_t)xx * XS)
                   : make_uint2(0u, 0u);
        }
#pragma unroll
        for (int i = 0; i < W + 2 * TAIL; ++i) {
            asm volatile("" : "+v"(raw[i].x), "+v"(raw[i].y));
        }
        __builtin_amdgcn_sched_barrier(0);
#pragma unroll
        for (int i = 0; i < W + 2 * TAIL; ++i) v[i] = h4f(raw[i]);
    } else {
        const float* src = (const float*)srcv;
#pragma unroll
        for (int i = 0; i < W + 2 * TAIL; ++i) {
            const int xx = x0 - TAIL + i;
            v[i] = (xx >= 0 && xx < X_) ? ld4(src + base + (size_t)xx * XS) : f4zero();
        }
#pragma unroll
        for (int i = 0; i < W + 2 * TAIL; ++i) {
            asm volatile("" : "+v"(v[i].x), "+v"(v[i].y), "+v"(v[i].z), "+v"(v[i].w));
        }
        __builtin_amdgcn_sched_barrier(0);
    }

    int pp = 0;
#pragma unroll
    for (int j = 0; j < W; ++j) {
        float4 acc = f4zero();
#pragma unroll
        for (int i = 0; i < KTAPS; ++i) fma4(acc, tp.k[i], v[j + i]);

        if (DOZ) {
            st4(&row[pp][t << 2], acc);
            asm volatile("s_waitcnt lgkmcnt(0)" ::: "memory");
            __builtin_amdgcn_s_barrier();
            __builtin_amdgcn_sched_barrier(0);

            float4 zacc = f4zero();
#pragma unroll
            for (int i = 0; i < KTAPS; ++i) {
                const int zz = z - TAIL + i;
                if (zz >= 0 && zz < Z_) {
                    fma4(zacc, tp.k[i], ld4(&row[pp][(zz << 3) + cw]));
                }
            }
            st4(dst + base + (size_t)(x0 + j) * XS, zacc);
            pp ^= 1;
        } else {
            st4(dst + base + (size_t)(x0 + j) * XS, acc);
        }
    }
}

// -------- Fallback-only: fused Y+Z, single plane per block, in-place-safe ----
template <int SEGY, int P>
__global__ __launch_bounds__(256) void yzconv_kernel(const float* __restrict__ src,
                                                     float* __restrict__ dst,
                                                     Taps tp) {
    __shared__ float row[2][ZC];

    const int t    = threadIdx.x;
    const int s    = blockIdx.x % SEGY;
    const int rest = blockIdx.x / SEGY;
    const int x    = rest & (X_ - 1);
    const int b    = rest >> 7;

    const int pbase = b * BS + x * XS;
    const int zc    = t << 2;
    const int z     = t >> 1;
    const int cw    = (t & 1) << 2;

    const int ylen = Y_ / SEGY;
    const int y0   = s * ylen;

    auto ldrow = [&](int yy) -> float4 {
        return (yy >= 0 && yy < Y_) ? ld4(src + pbase + yy * ZC + zc) : f4zero();
    };

    float4 w[KTAPS];
#pragma unroll
    for (int i = 0; i < KTAPS - 1; ++i) w[i] = ldrow(y0 - TAIL + i);
    float4 pf[P];
#pragma unroll
    for (int i = 0; i < P; ++i) pf[i] = ldrow(y0 + TAIL + i);

    int p = 0;
    for (int yy = 0; yy < ylen; yy += P) {
#pragma unroll
        for (int k = 0; k < P; ++k) {
            const int y = y0 + yy + k;
            w[KTAPS - 1] = pf[k];
            pf[k] = ldrow(y + TAIL + P);

            float4 acc = f4zero();
#pragma unroll
            for (int i = 0; i < KTAPS; ++i) fma4(acc, tp.k[i], w[i]);
            st4(&row[p][zc], acc);
            asm volatile("s_waitcnt lgkmcnt(0)" ::: "memory");
            __builtin_amdgcn_s_barrier();
            __builtin_amdgcn_sched_barrier(0);

            float4 zacc = f4zero();
#pragma unroll
            for (int i = 0; i < KTAPS; ++i) {
                const int zz = z - TAIL + i;
                if (zz >= 0 && zz < Z_) {
                    fma4(zacc, tp.k[i], ld4(&row[p][(zz << 3) + cw]));
                }
            }
            st4(dst + pbase + y * ZC + zc, zacc);

#pragma unroll
            for (int i = 0; i < KTAPS - 1; ++i) w[i] = w[i + 1];
            p ^= 1;
        }
    }
}

extern "C" void kernel_launch(void* const* d_in, const int* in_sizes, int n_in,
                              void* d_out, int out_size, void* d_ws, size_t ws_size,
                              hipStream_t stream) {
    const float* in = (const float*)d_in[0];
    float* out = (float*)d_out;

    // Gaussian taps: tail = int(2.0*3.0 + 0.5) = 6, K = 13, sigma = 2
    Taps tp;
    {
        float kv[KTAPS];
        float sum = 0.f;
        for (int i = 0; i < KTAPS; ++i) {
            const float xx = (float)(i - TAIL);
            kv[i] = expf(-0.5f * xx * xx / 4.0f);
            sum += kv[i];
        }
        for (int i = 0; i < KTAPS; ++i) tp.k[i] = kv[i] / sum;
    }

    const size_t need_bytes = (size_t)B_ * BS * sizeof(__half);  // 67 MB
    const bool use_ws = (ws_size >= need_bytes) && (d_ws != nullptr);

    if (use_ws) {
        __half* tmp = (__half*)d_ws;
        // Pass 1: plain cached Y conv, in (cold, fp32) -> tmp (fp16, cached).
        ystream<8><<<4096, 256, 0, stream>>>(in, tmp, tp);
        // Pass 2: X gather (fp16 tmp, L3-resident) + Z via LDS -> out (fp32).
        xzconv<16, true, true><<<B_ * (X_ / 16) * Y_, 256, 0, stream>>>(tmp, out, tp);
    } else {
        // Fallback: fp32 X-only gather in->out, then in-place fused Y+Z.
        xzconv<16, false, false><<<B_ * (X_ / 16) * Y_, 256, 0, stream>>>(in, out, tp);
        yzconv_kernel<1, 4><<<B_ * X_, 256, 0, stream>>>(out, out, tp);
    }
}